// Round 12
// baseline (293.789 us; speedup 1.0000x reference)
//
#include <hip/hip_runtime.h>
#include <hip/hip_bf16.h>
#include <stdint.h>

#define T_TOK 4096
#define D_DIM 1024
#define E_NUM 8
#define F_DIM 512
#define SH_DIM 1024
#define SCALE_F 2.5f

#define BM 128
#define BN 128
#define BK 32
#define TILE_E (BM * BK)   // elements per LDS tile buffer (8 KB)

#define NBIG (E_NUM * F_DIM * D_DIM)   // 4194304
#define NSML (SH_DIM * D_DIM)          // 1048576
#define NCONV_CHUNKS ((3 * NBIG + 3 * NSML) / 4)  // 3932160
#define MAX_TILES 72

// grid split points
#define UP_SHARED_BLOCKS 256                    // 32 m-tiles x 8 n-chunks (SH=1024)
#define UP_TOTAL (UP_SHARED_BLOCKS + MAX_TILES * 4)   // routed: 72 x (512/128)
#define DN_SHARED_BLOCKS 256                    // 32 m-tiles x 8 n-chunks (D=1024)
#define DN_TOTAL (DN_SHARED_BLOCKS + MAX_TILES * 8)   // routed: 72 x (1024/128)

typedef unsigned short ushort_t;
typedef __attribute__((ext_vector_type(8))) short short8;
typedef __attribute__((ext_vector_type(4))) short short4v;
typedef __attribute__((ext_vector_type(4))) float f32x4;

// global_load_lds, 16B per lane: LDS dest = uniform base + lane*16 (linear).
#define GLL16(g, l)                                                                  \
  __builtin_amdgcn_global_load_lds(                                                  \
      (const __attribute__((address_space(1))) void*)(g),                            \
      (__attribute__((address_space(3))) void*)(l), 16, 0, 0)

__device__ inline ushort_t f2bf(float f) {
  union { float f; unsigned u; } cv; cv.f = f;
  unsigned u = cv.u;
  unsigned r = (u + 0x7FFFu + ((u >> 16) & 1u)) >> 16;  // RNE
  return (ushort_t)r;
}

// ---------------- gate (f32 exact) + x -> bf16 ----------------
__global__ void gate_kernel(const float* __restrict__ x, const float* __restrict__ gw,
                            const float* __restrict__ gb, float* __restrict__ ew,
                            ushort_t* __restrict__ xb) {
  int t = blockIdx.x;
  int lane = threadIdx.x;  // 64 threads
  const float* xr = x + (size_t)t * D_DIM;
  float xv[16];
#pragma unroll
  for (int i = 0; i < 16; i++) xv[i] = xr[lane + (i << 6)];
#pragma unroll
  for (int i = 0; i < 16; i++) xb[(size_t)t * D_DIM + lane + (i << 6)] = f2bf(xv[i]);
  float logit[E_NUM];
#pragma unroll
  for (int e = 0; e < E_NUM; e++) {
    const float* wr = gw + (size_t)e * D_DIM;
    float s = 0.f;
#pragma unroll
    for (int i = 0; i < 16; i++) s += xv[i] * wr[lane + (i << 6)];
#pragma unroll
    for (int off = 32; off; off >>= 1) s += __shfl_xor(s, off, 64);
    logit[e] = s;
  }
  if (lane == 0) {
    float scores[E_NUM], sc[E_NUM];
#pragma unroll
    for (int e = 0; e < E_NUM; e++) {
      scores[e] = 1.f / (1.f + expf(-logit[e]));
      sc[e] = scores[e] + gb[e];
    }
    float gs[4];
#pragma unroll
    for (int g = 0; g < 4; g++) gs[g] = sc[2 * g] + sc[2 * g + 1];
    int g0 = 0;
#pragma unroll
    for (int g = 1; g < 4; g++) if (gs[g] > gs[g0]) g0 = g;
    int g1 = -1;
#pragma unroll
    for (int g = 0; g < 4; g++) { if (g == g0) continue; if (g1 < 0 || gs[g] > gs[g1]) g1 = g; }
    float tmp[E_NUM];
#pragma unroll
    for (int e = 0; e < E_NUM; e++) {
      int g = e >> 1;
      tmp[e] = (g == g0 || g == g1) ? sc[e] : 0.f;
    }
    int e0 = 0;
#pragma unroll
    for (int e = 1; e < E_NUM; e++) if (tmp[e] > tmp[e0]) e0 = e;
    int e1 = -1;
#pragma unroll
    for (int e = 0; e < E_NUM; e++) { if (e == e0) continue; if (e1 < 0 || tmp[e] > tmp[e1]) e1 = e; }
    float w0 = scores[e0], w1v = scores[e1];
    float inv = SCALE_F / (w0 + w1v + 1e-20f);
    float o[E_NUM];
#pragma unroll
    for (int e = 0; e < E_NUM; e++) o[e] = 0.f;
    o[e0] = w0 * inv;
    o[e1] = w1v * inv;
#pragma unroll
    for (int e = 0; e < E_NUM; e++) ew[t * E_NUM + e] = o[e];
  }
}

// ---------------- weight f32 -> bf16 conversion ----------------
__global__ void convert_kernel(const float* __restrict__ w1, const float* __restrict__ w2,
                               const float* __restrict__ w3, const float* __restrict__ sg,
                               const float* __restrict__ su, const float* __restrict__ sd,
                               ushort_t* __restrict__ w1b, ushort_t* __restrict__ w2b,
                               ushort_t* __restrict__ w3b, ushort_t* __restrict__ sgb,
                               ushort_t* __restrict__ sub, ushort_t* __restrict__ sdb) {
  size_t chunk = (size_t)blockIdx.x * blockDim.x + threadIdx.x;
  if (chunk >= (size_t)NCONV_CHUNKS) return;
  size_t idx = chunk * 4;
  const float* src; ushort_t* dst;
  if (idx < (size_t)NBIG)                    { src = w1; dst = w1b; }
  else if (idx < 2ull * NBIG)                { src = w2; dst = w2b; idx -= (size_t)NBIG; }
  else if (idx < 3ull * NBIG)                { src = w3; dst = w3b; idx -= 2ull * NBIG; }
  else if (idx < 3ull * NBIG + NSML)         { src = sg; dst = sgb; idx -= 3ull * NBIG; }
  else if (idx < 3ull * NBIG + 2ull * NSML)  { src = su; dst = sub; idx -= 3ull * NBIG + NSML; }
  else                                       { src = sd; dst = sdb; idx -= 3ull * NBIG + 2ull * NSML; }
  f32x4 v = *(const f32x4*)&src[idx];
  short4v o;
  o[0] = (short)f2bf(v[0]); o[1] = (short)f2bf(v[1]);
  o[2] = (short)f2bf(v[2]); o[3] = (short)f2bf(v[3]);
  *(short4v*)&dst[idx] = o;
}

// ---------------- expert token lists ----------------
__global__ void build_lists(const float* __restrict__ ew, int* __restrict__ counts,
                            int* __restrict__ toklist) {
  int t = blockIdx.x * blockDim.x + threadIdx.x;
  if (t >= T_TOK) return;
#pragma unroll
  for (int e = 0; e < E_NUM; e++) {
    if (ew[t * E_NUM + e] > 0.f) {
      int p = atomicAdd(&counts[e], 1);
      toklist[e * T_TOK + p] = t;
    }
  }
}

__global__ void assign_kernel(const int* __restrict__ counts, int4* __restrict__ assign,
                              int* __restrict__ meta) {
  if (threadIdx.x != 0 || blockIdx.x != 0) return;
  int total = 0, base = 0;
  for (int e = 0; e < E_NUM; e++) {
    int c = counts[e];
    int nt = (c + BM - 1) / BM;
    for (int i = 0; i < nt; i++) {
      assign[total] = make_int4(e, i, base, c);
      total++;
    }
    base += nt * BM;
  }
  meta[0] = total;
}

// ---------------- fused up-proj: gll + swizzled LDS + 2-phase prefetch ----------------
// LDS [2][128][32] bf16 per operand. Swizzle: 16B-chunk c' = c ^ ((row>>1)&3),
// applied to the GLOBAL source and the ds_read address; gll dest stays linear.
// K-loop: stage(t+1) -> compute(t) -> ONE __syncthreads (drains vmcnt) -> swap.
__global__ __launch_bounds__(256, 2)
void up_gemm(const ushort_t* __restrict__ xb,
             const ushort_t* __restrict__ sgb, const ushort_t* __restrict__ sub,
             const ushort_t* __restrict__ w1b, const ushort_t* __restrict__ w3b,
             const int* __restrict__ toklist,
             const int4* __restrict__ assign, const int* __restrict__ meta,
             ushort_t* __restrict__ hsh, ushort_t* __restrict__ hbuf) {
  __shared__ ushort_t la[2 * TILE_E], lb1[2 * TILE_E], lb2[2 * TILE_E];
  __shared__ int ttok[BM];
  int bid = blockIdx.x;
  int tid = threadIdx.x, wid = tid >> 6, lane = tid & 63;

  const ushort_t *b1base, *b2base;
  ushort_t* dst;
  int n0, dstride;
  size_t rowbase;

  if (bid < UP_SHARED_BLOCKS) {
    int m0 = (bid >> 3) * BM;
    n0 = (bid & 7) * BN;
    b1base = sgb + (size_t)n0 * D_DIM;
    b2base = sub + (size_t)n0 * D_DIM;
    dst = hsh; dstride = SH_DIM; rowbase = m0;
    if (tid < BM) ttok[tid] = m0 + tid;
  } else {
    int rid = bid - UP_SHARED_BLOCKS;
    int tidx = rid >> 2;
    if (tidx >= meta[0]) return;
    int4 as = assign[tidx];
    int e = as.x, tile = as.y, sbase = as.z, cnt = as.w;
    n0 = (rid & 3) * BN;
    b1base = w1b + ((size_t)e * F_DIM + n0) * D_DIM;
    b2base = w3b + ((size_t)e * F_DIM + n0) * D_DIM;
    dst = hbuf; dstride = F_DIM; rowbase = (size_t)sbase + (size_t)tile * BM;
    if (tid < BM) {
      int idx = tile * BM + tid;
      ttok[tid] = (idx < cnt) ? toklist[e * T_TOK + idx] : -1;
    }
  }
  __syncthreads();

  // --- fixed per-lane staging geometry (rows srow, srow+16; chunk c16) ---
  int srow = (wid << 5) + (lane >> 2);
  int c16 = lane & 3;
  int s0 = c16 ^ ((srow >> 1) & 3);
  int s1 = c16 ^ (((srow + 16) >> 1) & 3);
  int tka = ttok[srow], tkb = ttok[srow + 16];
  const ushort_t* gA0 = xb + (size_t)(tka < 0 ? 0 : tka) * D_DIM + (s0 << 3);
  const ushort_t* gA1 = xb + (size_t)(tkb < 0 ? 0 : tkb) * D_DIM + (s1 << 3);
  const ushort_t* gB1a = b1base + (size_t)srow * D_DIM + (s0 << 3);
  const ushort_t* gB1b = b1base + (size_t)(srow + 16) * D_DIM + (s1 << 3);
  const ushort_t* gB2a = b2base + (size_t)srow * D_DIM + (s0 << 3);
  const ushort_t* gB2b = b2base + (size_t)(srow + 16) * D_DIM + (s1 << 3);
  int wo0 = (wid << 10);        // wave's first 16 rows (1024 B = 512 elems x2B)
  int wo1 = (wid << 10) + 512;  // wave's second 16 rows

  // --- fixed per-lane fragment read offsets (swizzled, within one buffer) ---
  int wm = (wid >> 1) << 6, wn = (wid & 1) << 6;
  int rsel = lane & 15, g = lane >> 4;
  int offA[4], offB[4];
#pragma unroll
  for (int i = 0; i < 4; i++) {
    int R = wm + i * 16 + rsel;
    offA[i] = (R << 5) + ((g ^ ((R >> 1) & 3)) << 3);
    int R2 = wn + i * 16 + rsel;
    offB[i] = (R2 << 5) + ((g ^ ((R2 >> 1) & 3)) << 3);
  }

  f32x4 acc1[4][4] = {{{0.f}}}, acc2[4][4] = {{{0.f}}};

  // prologue: stage tile 0 into buffer 0
  GLL16(gA0, la + wo0);   GLL16(gA1, la + wo1);
  GLL16(gB1a, lb1 + wo0); GLL16(gB1b, lb1 + wo1);
  GLL16(gB2a, lb2 + wo0); GLL16(gB2b, lb2 + wo1);
  gA0 += BK; gA1 += BK; gB1a += BK; gB1b += BK; gB2a += BK; gB2b += BK;
  __syncthreads();

  const int NT = D_DIM / BK;  // 32
  int cur = 0;
  for (int t = 0; t < NT; ++t) {
    int nxt = cur ^ TILE_E;
    if (t + 1 < NT) {  // stage t+1 into the other buffer (flows during compute)
      GLL16(gA0, la + nxt + wo0);   GLL16(gA1, la + nxt + wo1);
      GLL16(gB1a, lb1 + nxt + wo0); GLL16(gB1b, lb1 + nxt + wo1);
      GLL16(gB2a, lb2 + nxt + wo0); GLL16(gB2b, lb2 + nxt + wo1);
      gA0 += BK; gA1 += BK; gB1a += BK; gB1b += BK; gB2a += BK; gB2b += BK;
    }
    short8 af[4], bf1[4], bf2[4];
#pragma unroll
    for (int i = 0; i < 4; i++) {
      af[i]  = *(const short8*)&la[cur + offA[i]];
      bf1[i] = *(const short8*)&lb1[cur + offB[i]];
      bf2[i] = *(const short8*)&lb2[cur + offB[i]];
    }
#pragma unroll
    for (int mi = 0; mi < 4; mi++)
#pragma unroll
      for (int ni = 0; ni < 4; ni++) {
        acc1[mi][ni] = __builtin_amdgcn_mfma_f32_16x16x32_bf16(af[mi], bf1[ni], acc1[mi][ni], 0, 0, 0);
        acc2[mi][ni] = __builtin_amdgcn_mfma_f32_16x16x32_bf16(af[mi], bf2[ni], acc2[mi][ni], 0, 0, 0);
      }
    __syncthreads();  // drains prefetch vmcnt + protects cur buffer for overwrite
    cur = nxt;
  }

  int cw = lane & 15, rw = (lane >> 4) << 2;
#pragma unroll
  for (int mi = 0; mi < 4; mi++)
#pragma unroll
    for (int ni = 0; ni < 4; ni++)
#pragma unroll
      for (int r = 0; r < 4; r++) {
        int lrow = wm + mi * 16 + rw + r;
        int col = n0 + wn + ni * 16 + cw;
        float gg = acc1[mi][ni][r], u = acc2[mi][ni][r];
        float h = gg * (1.f / (1.f + __expf(-gg))) * u;
        dst[(rowbase + lrow) * (size_t)dstride + col] = f2bf(h);
      }
}

// ---------------- fused down-proj: gll + 2-phase prefetch, all atomicAdd ----------------
__global__ __launch_bounds__(256, 2)
void down_gemm(const ushort_t* __restrict__ hsh, const ushort_t* __restrict__ hbuf,
               const ushort_t* __restrict__ sdb, const ushort_t* __restrict__ w2b,
               const int* __restrict__ toklist, const float* __restrict__ ew,
               const int4* __restrict__ assign, const int* __restrict__ meta,
               float* __restrict__ out) {
  __shared__ ushort_t la[2 * TILE_E], lb[2 * TILE_E];
  __shared__ int ttok[BM];
  __shared__ float twt[BM];
  int bid = blockIdx.x;
  int tid = threadIdx.x, wid = tid >> 6, lane = tid & 63;

  const ushort_t *abase, *bbase;
  int n0, kend;

  if (bid < DN_SHARED_BLOCKS) {
    int m0 = (bid >> 3) * BM;
    n0 = (bid & 7) * BN;
    abase = hsh + (size_t)m0 * SH_DIM;
    bbase = sdb + (size_t)n0 * SH_DIM;
    kend = SH_DIM;
    if (tid < BM) { ttok[tid] = m0 + tid; twt[tid] = 1.f; }
  } else {
    int rid = bid - DN_SHARED_BLOCKS;
    int tidx = rid >> 3;
    if (tidx >= meta[0]) return;
    int4 as = assign[tidx];
    int e = as.x, tile = as.y, sbase = as.z, cnt = as.w;
    n0 = (rid & 7) * BN;
    abase = hbuf + ((size_t)sbase + (size_t)tile * BM) * F_DIM;
    bbase = w2b + ((size_t)e * D_DIM + n0) * F_DIM;
    kend = F_DIM;
    if (tid < BM) {
      int idx = tile * BM + tid;
      int tk = (idx < cnt) ? toklist[e * T_TOK + idx] : -1;
      ttok[tid] = tk;
      twt[tid] = (tk >= 0) ? ew[tk * E_NUM + e] : 0.f;
    }
  }
  __syncthreads();

  int srow = (wid << 5) + (lane >> 2);
  int c16 = lane & 3;
  int s0 = c16 ^ ((srow >> 1) & 3);
  int s1 = c16 ^ (((srow + 16) >> 1) & 3);
  const ushort_t* gA0 = abase + (size_t)srow * kend + (s0 << 3);
  const ushort_t* gA1 = abase + (size_t)(srow + 16) * kend + (s1 << 3);
  const ushort_t* gB0 = bbase + (size_t)srow * kend + (s0 << 3);
  const ushort_t* gB1 = bbase + (size_t)(srow + 16) * kend + (s1 << 3);
  int wo0 = (wid << 10);
  int wo1 = (wid << 10) + 512;

  int wm = (wid >> 1) << 6, wn = (wid & 1) << 6;
  int rsel = lane & 15, g = lane >> 4;
  int offA[4], offB[4];
#pragma unroll
  for (int i = 0; i < 4; i++) {
    int R = wm + i * 16 + rsel;
    offA[i] = (R << 5) + ((g ^ ((R >> 1) & 3)) << 3);
    int R2 = wn + i * 16 + rsel;
    offB[i] = (R2 << 5) + ((g ^ ((R2 >> 1) & 3)) << 3);
  }

  f32x4 acc[4][4] = {{{0.f}}};

  GLL16(gA0, la + wo0); GLL16(gA1, la + wo1);
  GLL16(gB0, lb + wo0); GLL16(gB1, lb + wo1);
  gA0 += BK; gA1 += BK; gB0 += BK; gB1 += BK;
  __syncthreads();

  const int NT = kend / BK;
  int cur = 0;
  for (int t = 0; t < NT; ++t) {
    int nxt = cur ^ TILE_E;
    if (t + 1 < NT) {
      GLL16(gA0, la + nxt + wo0); GLL16(gA1, la + nxt + wo1);
      GLL16(gB0, lb + nxt + wo0); GLL16(gB1, lb + nxt + wo1);
      gA0 += BK; gA1 += BK; gB0 += BK; gB1 += BK;
    }
    short8 af[4], bf[4];
#pragma unroll
    for (int i = 0; i < 4; i++) {
      af[i] = *(const short8*)&la[cur + offA[i]];
      bf[i] = *(const short8*)&lb[cur + offB[i]];
    }
#pragma unroll
    for (int mi = 0; mi < 4; mi++)
#pragma unroll
      for (int ni = 0; ni < 4; ni++)
        acc[mi][ni] = __builtin_amdgcn_mfma_f32_16x16x32_bf16(af[mi], bf[ni], acc[mi][ni], 0, 0, 0);
    __syncthreads();
    cur = nxt;
  }

  int cw = lane & 15, rw = (lane >> 4) << 2;
#pragma unroll
  for (int mi = 0; mi < 4; mi++)
#pragma unroll
    for (int ni = 0; ni < 4; ni++)
#pragma unroll
      for (int r = 0; r < 4; r++) {
        int lrow = wm + mi * 16 + rw + r;
        int tk = ttok[lrow];
        if (tk >= 0) {
          int col = n0 + wn + ni * 16 + cw;
          atomicAdd(&out[(size_t)tk * D_DIM + col], twt[lrow] * acc[mi][ni][r]);
        }
      }
}

extern "C" void kernel_launch(void* const* d_in, const int* in_sizes, int n_in,
                              void* d_out, int out_size, void* d_ws, size_t ws_size,
                              hipStream_t stream) {
  const float* x  = (const float*)d_in[0];
  const float* gw = (const float*)d_in[1];
  const float* gb = (const float*)d_in[2];
  const float* w1 = (const float*)d_in[3];
  const float* w2 = (const float*)d_in[4];
  const float* w3 = (const float*)d_in[5];
  const float* sg = (const float*)d_in[6];
  const float* su = (const float*)d_in[7];
  const float* sd = (const float*)d_in[8];
  float* out = (float*)d_out;

  char* ws = (char*)d_ws;
  size_t off = 0;
  auto alloc = [&](size_t bytes) {
    char* p = ws + off;
    off += (bytes + 255) & ~(size_t)255;
    return p;
  };
  ushort_t* xb   = (ushort_t*)alloc((size_t)T_TOK * D_DIM * 2);
  ushort_t* w1b  = (ushort_t*)alloc((size_t)NBIG * 2);
  ushort_t* w2b  = (ushort_t*)alloc((size_t)NBIG * 2);
  ushort_t* w3b  = (ushort_t*)alloc((size_t)NBIG * 2);
  ushort_t* sgb  = (ushort_t*)alloc((size_t)NSML * 2);
  ushort_t* sub  = (ushort_t*)alloc((size_t)NSML * 2);
  ushort_t* sdb  = (ushort_t*)alloc((size_t)NSML * 2);
  float*    ew   = (float*)alloc((size_t)T_TOK * E_NUM * 4);
  ushort_t* hsh  = (ushort_t*)alloc((size_t)T_TOK * SH_DIM * 2);
  ushort_t* hbuf = (ushort_t*)alloc((size_t)MAX_TILES * BM * F_DIM * 2);
  int*      toklist = (int*)alloc((size_t)E_NUM * T_TOK * 4);
  int*      counts  = (int*)alloc(64);
  int4*     assign  = (int4*)alloc((MAX_TILES + 8) * sizeof(int4));
  int*      meta    = (int*)alloc(64);

  hipMemsetAsync(counts, 0, 64, stream);
  hipMemsetAsync(out, 0, (size_t)out_size * sizeof(float), stream);
  gate_kernel<<<T_TOK, 64, 0, stream>>>(x, gw, gb, ew, xb);
  convert_kernel<<<NCONV_CHUNKS / 256, 256, 0, stream>>>(w1, w2, w3, sg, su, sd,
                                                         w1b, w2b, w3b, sgb, sub, sdb);
  build_lists<<<(T_TOK + 255) / 256, 256, 0, stream>>>(ew, counts, toklist);
  assign_kernel<<<1, 64, 0, stream>>>(counts, assign, meta);
  up_gemm<<<UP_TOTAL, 256, 0, stream>>>(xb, sgb, sub, w1b, w3b, toklist, assign, meta,
                                        hsh, hbuf);
  down_gemm<<<DN_TOTAL, 256, 0, stream>>>(hsh, hbuf, sdb, w2b, toklist, ew, assign, meta,
                                          out);
}

// Round 13
// 276.526 us; speedup vs baseline: 1.0624x; 1.0624x over previous
//
#include <hip/hip_runtime.h>
#include <hip/hip_bf16.h>
#include <stdint.h>

#define T_TOK 4096
#define D_DIM 1024
#define E_NUM 8
#define F_DIM 512
#define SH_DIM 1024
#define SCALE_F 2.5f

#define BM 128
#define BN 128
#define BK 32
#define TILE_E (BM * BK)   // elements per LDS tile buffer (8 KB)

#define NBIG (E_NUM * F_DIM * D_DIM)   // 4194304
#define NSML (SH_DIM * D_DIM)          // 1048576
#define NCONV_CHUNKS ((3 * NBIG + 3 * NSML) / 4)  // 3932160
#define MAX_TILES 72

// grid split points
#define UP_SHARED_BLOCKS 256                    // 32 m-tiles x 8 n-chunks (SH=1024)
#define UP_TOTAL (UP_SHARED_BLOCKS + MAX_TILES * 4)   // routed: 72 x (512/128)
#define DN_SHARED_BLOCKS 256                    // 32 m-tiles x 8 n-chunks (D=1024)
#define DN_TOTAL (DN_SHARED_BLOCKS + MAX_TILES * 8)   // routed: 72 x (1024/128)

typedef unsigned short ushort_t;
typedef __attribute__((ext_vector_type(8))) short short8;
typedef __attribute__((ext_vector_type(4))) short short4v;
typedef __attribute__((ext_vector_type(4))) float f32x4;

// global_load_lds, 16B per lane: LDS dest = uniform base + lane*16 (linear).
#define GLL16(g, l)                                                                  \
  __builtin_amdgcn_global_load_lds(                                                  \
      (const __attribute__((address_space(1))) void*)(g),                            \
      (__attribute__((address_space(3))) void*)(l), 16, 0, 0)

// counted vmcnt: keep N loads in flight across the barrier (T4 mechanism).
#define WAIT_VM(N) asm volatile("s_waitcnt vmcnt(" #N ")" ::: "memory")
#define CFENCE()   asm volatile("" ::: "memory")

__device__ inline ushort_t f2bf(float f) {
  union { float f; unsigned u; } cv; cv.f = f;
  unsigned u = cv.u;
  unsigned r = (u + 0x7FFFu + ((u >> 16) & 1u)) >> 16;  // RNE
  return (ushort_t)r;
}

// ---------------- gate (f32 exact) + x -> bf16 ----------------
__global__ void gate_kernel(const float* __restrict__ x, const float* __restrict__ gw,
                            const float* __restrict__ gb, float* __restrict__ ew,
                            ushort_t* __restrict__ xb) {
  int t = blockIdx.x;
  int lane = threadIdx.x;  // 64 threads
  const float* xr = x + (size_t)t * D_DIM;
  float xv[16];
#pragma unroll
  for (int i = 0; i < 16; i++) xv[i] = xr[lane + (i << 6)];
#pragma unroll
  for (int i = 0; i < 16; i++) xb[(size_t)t * D_DIM + lane + (i << 6)] = f2bf(xv[i]);
  float logit[E_NUM];
#pragma unroll
  for (int e = 0; e < E_NUM; e++) {
    const float* wr = gw + (size_t)e * D_DIM;
    float s = 0.f;
#pragma unroll
    for (int i = 0; i < 16; i++) s += xv[i] * wr[lane + (i << 6)];
#pragma unroll
    for (int off = 32; off; off >>= 1) s += __shfl_xor(s, off, 64);
    logit[e] = s;
  }
  if (lane == 0) {
    float scores[E_NUM], sc[E_NUM];
#pragma unroll
    for (int e = 0; e < E_NUM; e++) {
      scores[e] = 1.f / (1.f + expf(-logit[e]));
      sc[e] = scores[e] + gb[e];
    }
    float gs[4];
#pragma unroll
    for (int g = 0; g < 4; g++) gs[g] = sc[2 * g] + sc[2 * g + 1];
    int g0 = 0;
#pragma unroll
    for (int g = 1; g < 4; g++) if (gs[g] > gs[g0]) g0 = g;
    int g1 = -1;
#pragma unroll
    for (int g = 0; g < 4; g++) { if (g == g0) continue; if (g1 < 0 || gs[g] > gs[g1]) g1 = g; }
    float tmp[E_NUM];
#pragma unroll
    for (int e = 0; e < E_NUM; e++) {
      int g = e >> 1;
      tmp[e] = (g == g0 || g == g1) ? sc[e] : 0.f;
    }
    int e0 = 0;
#pragma unroll
    for (int e = 1; e < E_NUM; e++) if (tmp[e] > tmp[e0]) e0 = e;
    int e1 = -1;
#pragma unroll
    for (int e = 0; e < E_NUM; e++) { if (e == e0) continue; if (e1 < 0 || tmp[e] > tmp[e1]) e1 = e; }
    float w0 = scores[e0], w1v = scores[e1];
    float inv = SCALE_F / (w0 + w1v + 1e-20f);
    float o[E_NUM];
#pragma unroll
    for (int e = 0; e < E_NUM; e++) o[e] = 0.f;
    o[e0] = w0 * inv;
    o[e1] = w1v * inv;
#pragma unroll
    for (int e = 0; e < E_NUM; e++) ew[t * E_NUM + e] = o[e];
  }
}

// ---------------- weight f32 -> bf16 conversion ----------------
__global__ void convert_kernel(const float* __restrict__ w1, const float* __restrict__ w2,
                               const float* __restrict__ w3, const float* __restrict__ sg,
                               const float* __restrict__ su, const float* __restrict__ sd,
                               ushort_t* __restrict__ w1b, ushort_t* __restrict__ w2b,
                               ushort_t* __restrict__ w3b, ushort_t* __restrict__ sgb,
                               ushort_t* __restrict__ sub, ushort_t* __restrict__ sdb) {
  size_t chunk = (size_t)blockIdx.x * blockDim.x + threadIdx.x;
  if (chunk >= (size_t)NCONV_CHUNKS) return;
  size_t idx = chunk * 4;
  const float* src; ushort_t* dst;
  if (idx < (size_t)NBIG)                    { src = w1; dst = w1b; }
  else if (idx < 2ull * NBIG)                { src = w2; dst = w2b; idx -= (size_t)NBIG; }
  else if (idx < 3ull * NBIG)                { src = w3; dst = w3b; idx -= 2ull * NBIG; }
  else if (idx < 3ull * NBIG + NSML)         { src = sg; dst = sgb; idx -= 3ull * NBIG; }
  else if (idx < 3ull * NBIG + 2ull * NSML)  { src = su; dst = sub; idx -= 3ull * NBIG + NSML; }
  else                                       { src = sd; dst = sdb; idx -= 3ull * NBIG + 2ull * NSML; }
  f32x4 v = *(const f32x4*)&src[idx];
  short4v o;
  o[0] = (short)f2bf(v[0]); o[1] = (short)f2bf(v[1]);
  o[2] = (short)f2bf(v[2]); o[3] = (short)f2bf(v[3]);
  *(short4v*)&dst[idx] = o;
}

// ---------------- expert token lists ----------------
__global__ void build_lists(const float* __restrict__ ew, int* __restrict__ counts,
                            int* __restrict__ toklist) {
  int t = blockIdx.x * blockDim.x + threadIdx.x;
  if (t >= T_TOK) return;
#pragma unroll
  for (int e = 0; e < E_NUM; e++) {
    if (ew[t * E_NUM + e] > 0.f) {
      int p = atomicAdd(&counts[e], 1);
      toklist[e * T_TOK + p] = t;
    }
  }
}

__global__ void assign_kernel(const int* __restrict__ counts, int4* __restrict__ assign,
                              int* __restrict__ meta) {
  if (threadIdx.x != 0 || blockIdx.x != 0) return;
  int total = 0, base = 0;
  for (int e = 0; e < E_NUM; e++) {
    int c = counts[e];
    int nt = (c + BM - 1) / BM;
    for (int i = 0; i < nt; i++) {
      assign[total] = make_int4(e, i, base, c);
      total++;
    }
    base += nt * BM;
  }
  meta[0] = total;
}

// ---------------- fused up-proj: gll + swizzle + triple-buffer counted-vmcnt ----------------
// LDS [3][128][32] bf16 per operand. One raw s_barrier per K-step; vmcnt(6)
// keeps the next tile's 6 gll in flight across the barrier (never drains to 0
// in the loop). WAR safe: GLL(t+1) targets the buffer last read at t-2.
__global__ __launch_bounds__(256, 2)
void up_gemm(const ushort_t* __restrict__ xb,
             const ushort_t* __restrict__ sgb, const ushort_t* __restrict__ sub,
             const ushort_t* __restrict__ w1b, const ushort_t* __restrict__ w3b,
             const int* __restrict__ toklist,
             const int4* __restrict__ assign, const int* __restrict__ meta,
             ushort_t* __restrict__ hsh, ushort_t* __restrict__ hbuf) {
  __shared__ ushort_t la[3 * TILE_E], lb1[3 * TILE_E], lb2[3 * TILE_E];
  __shared__ int ttok[BM];
  int bid = blockIdx.x;
  int tid = threadIdx.x, wid = tid >> 6, lane = tid & 63;

  const ushort_t *b1base, *b2base;
  ushort_t* dst;
  int n0, dstride;
  size_t rowbase;

  if (bid < UP_SHARED_BLOCKS) {
    int m0 = (bid >> 3) * BM;
    n0 = (bid & 7) * BN;
    b1base = sgb + (size_t)n0 * D_DIM;
    b2base = sub + (size_t)n0 * D_DIM;
    dst = hsh; dstride = SH_DIM; rowbase = m0;
    if (tid < BM) ttok[tid] = m0 + tid;
  } else {
    int rid = bid - UP_SHARED_BLOCKS;
    int tidx = rid >> 2;
    if (tidx >= meta[0]) return;
    int4 as = assign[tidx];
    int e = as.x, tile = as.y, sbase = as.z, cnt = as.w;
    n0 = (rid & 3) * BN;
    b1base = w1b + ((size_t)e * F_DIM + n0) * D_DIM;
    b2base = w3b + ((size_t)e * F_DIM + n0) * D_DIM;
    dst = hbuf; dstride = F_DIM; rowbase = (size_t)sbase + (size_t)tile * BM;
    if (tid < BM) {
      int idx = tile * BM + tid;
      ttok[tid] = (idx < cnt) ? toklist[e * T_TOK + idx] : -1;
    }
  }
  __syncthreads();

  // --- fixed per-lane staging geometry (rows srow, srow+16; chunk c16) ---
  int srow = (wid << 5) + (lane >> 2);
  int c16 = lane & 3;
  int s0 = c16 ^ ((srow >> 1) & 3);
  int s1 = c16 ^ (((srow + 16) >> 1) & 3);
  int tka = ttok[srow], tkb = ttok[srow + 16];
  const ushort_t* gA0 = xb + (size_t)(tka < 0 ? 0 : tka) * D_DIM + (s0 << 3);
  const ushort_t* gA1 = xb + (size_t)(tkb < 0 ? 0 : tkb) * D_DIM + (s1 << 3);
  const ushort_t* gB1a = b1base + (size_t)srow * D_DIM + (s0 << 3);
  const ushort_t* gB1b = b1base + (size_t)(srow + 16) * D_DIM + (s1 << 3);
  const ushort_t* gB2a = b2base + (size_t)srow * D_DIM + (s0 << 3);
  const ushort_t* gB2b = b2base + (size_t)(srow + 16) * D_DIM + (s1 << 3);
  int wo0 = (wid << 10);        // wave's first 16 rows (1024 B = 512 elems x2B)
  int wo1 = (wid << 10) + 512;  // wave's second 16 rows

  // --- fixed per-lane fragment read offsets (swizzled, within one buffer) ---
  int wm = (wid >> 1) << 6, wn = (wid & 1) << 6;
  int rsel = lane & 15, g = lane >> 4;
  int offA[4], offB[4];
#pragma unroll
  for (int i = 0; i < 4; i++) {
    int R = wm + i * 16 + rsel;
    offA[i] = (R << 5) + ((g ^ ((R >> 1) & 3)) << 3);
    int R2 = wn + i * 16 + rsel;
    offB[i] = (R2 << 5) + ((g ^ ((R2 >> 1) & 3)) << 3);
  }

  f32x4 acc1[4][4] = {{{0.f}}}, acc2[4][4] = {{{0.f}}};

  // prologue: stage tile 0 into buffer 0 (no wait — vmcnt counted in loop)
  GLL16(gA0, la + wo0);   GLL16(gA1, la + wo1);
  GLL16(gB1a, lb1 + wo0); GLL16(gB1b, lb1 + wo1);
  GLL16(gB2a, lb2 + wo0); GLL16(gB2b, lb2 + wo1);
  gA0 += BK; gA1 += BK; gB1a += BK; gB1b += BK; gB2a += BK; gB2b += BK;

  const int NT = D_DIM / BK;  // 32
  int cur = 0;
  for (int t = 0; t < NT; ++t) {
    int nb = cur + 1; if (nb == 3) nb = 0;
    int nbase = nb * TILE_E;
    if (t + 1 < NT) {  // stage t+1; its 6 loads stay in flight across the barrier
      GLL16(gA0, la + nbase + wo0);   GLL16(gA1, la + nbase + wo1);
      GLL16(gB1a, lb1 + nbase + wo0); GLL16(gB1b, lb1 + nbase + wo1);
      GLL16(gB2a, lb2 + nbase + wo0); GLL16(gB2b, lb2 + nbase + wo1);
      gA0 += BK; gA1 += BK; gB1a += BK; gB1b += BK; gB2a += BK; gB2b += BK;
      WAIT_VM(6);   // tile t's 6 loads landed; t+1's may fly
    } else {
      WAIT_VM(0);   // last tile: everything landed
    }
    __builtin_amdgcn_s_barrier();
    CFENCE();
    int base = cur * TILE_E;
    short8 af[4], bf1[4], bf2[4];
#pragma unroll
    for (int i = 0; i < 4; i++) {
      af[i]  = *(const short8*)&la[base + offA[i]];
      bf1[i] = *(const short8*)&lb1[base + offB[i]];
      bf2[i] = *(const short8*)&lb2[base + offB[i]];
    }
#pragma unroll
    for (int mi = 0; mi < 4; mi++)
#pragma unroll
      for (int ni = 0; ni < 4; ni++) {
        acc1[mi][ni] = __builtin_amdgcn_mfma_f32_16x16x32_bf16(af[mi], bf1[ni], acc1[mi][ni], 0, 0, 0);
        acc2[mi][ni] = __builtin_amdgcn_mfma_f32_16x16x32_bf16(af[mi], bf2[ni], acc2[mi][ni], 0, 0, 0);
      }
    CFENCE();
    cur = nb;
  }

  int cw = lane & 15, rw = (lane >> 4) << 2;
#pragma unroll
  for (int mi = 0; mi < 4; mi++)
#pragma unroll
    for (int ni = 0; ni < 4; ni++)
#pragma unroll
      for (int r = 0; r < 4; r++) {
        int lrow = wm + mi * 16 + rw + r;
        int col = n0 + wn + ni * 16 + cw;
        float gg = acc1[mi][ni][r], u = acc2[mi][ni][r];
        float h = gg * (1.f / (1.f + __expf(-gg))) * u;
        dst[(rowbase + lrow) * (size_t)dstride + col] = f2bf(h);
      }
}

// ---------------- fused down-proj: triple-buffer counted-vmcnt, all atomicAdd ----------------
__global__ __launch_bounds__(256, 2)
void down_gemm(const ushort_t* __restrict__ hsh, const ushort_t* __restrict__ hbuf,
               const ushort_t* __restrict__ sdb, const ushort_t* __restrict__ w2b,
               const int* __restrict__ toklist, const float* __restrict__ ew,
               const int4* __restrict__ assign, const int* __restrict__ meta,
               float* __restrict__ out) {
  __shared__ ushort_t la[3 * TILE_E], lb[3 * TILE_E];
  __shared__ int ttok[BM];
  __shared__ float twt[BM];
  int bid = blockIdx.x;
  int tid = threadIdx.x, wid = tid >> 6, lane = tid & 63;

  const ushort_t *abase, *bbase;
  int n0, kend;

  if (bid < DN_SHARED_BLOCKS) {
    int m0 = (bid >> 3) * BM;
    n0 = (bid & 7) * BN;
    abase = hsh + (size_t)m0 * SH_DIM;
    bbase = sdb + (size_t)n0 * SH_DIM;
    kend = SH_DIM;
    if (tid < BM) { ttok[tid] = m0 + tid; twt[tid] = 1.f; }
  } else {
    int rid = bid - DN_SHARED_BLOCKS;
    int tidx = rid >> 3;
    if (tidx >= meta[0]) return;
    int4 as = assign[tidx];
    int e = as.x, tile = as.y, sbase = as.z, cnt = as.w;
    n0 = (rid & 7) * BN;
    abase = hbuf + ((size_t)sbase + (size_t)tile * BM) * F_DIM;
    bbase = w2b + ((size_t)e * D_DIM + n0) * F_DIM;
    kend = F_DIM;
    if (tid < BM) {
      int idx = tile * BM + tid;
      int tk = (idx < cnt) ? toklist[e * T_TOK + idx] : -1;
      ttok[tid] = tk;
      twt[tid] = (tk >= 0) ? ew[tk * E_NUM + e] : 0.f;
    }
  }
  __syncthreads();

  int srow = (wid << 5) + (lane >> 2);
  int c16 = lane & 3;
  int s0 = c16 ^ ((srow >> 1) & 3);
  int s1 = c16 ^ (((srow + 16) >> 1) & 3);
  const ushort_t* gA0 = abase + (size_t)srow * kend + (s0 << 3);
  const ushort_t* gA1 = abase + (size_t)(srow + 16) * kend + (s1 << 3);
  const ushort_t* gB0 = bbase + (size_t)srow * kend + (s0 << 3);
  const ushort_t* gB1 = bbase + (size_t)(srow + 16) * kend + (s1 << 3);
  int wo0 = (wid << 10);
  int wo1 = (wid << 10) + 512;

  int wm = (wid >> 1) << 6, wn = (wid & 1) << 6;
  int rsel = lane & 15, g = lane >> 4;
  int offA[4], offB[4];
#pragma unroll
  for (int i = 0; i < 4; i++) {
    int R = wm + i * 16 + rsel;
    offA[i] = (R << 5) + ((g ^ ((R >> 1) & 3)) << 3);
    int R2 = wn + i * 16 + rsel;
    offB[i] = (R2 << 5) + ((g ^ ((R2 >> 1) & 3)) << 3);
  }

  f32x4 acc[4][4] = {{{0.f}}};

  GLL16(gA0, la + wo0); GLL16(gA1, la + wo1);
  GLL16(gB0, lb + wo0); GLL16(gB1, lb + wo1);
  gA0 += BK; gA1 += BK; gB0 += BK; gB1 += BK;

  const int NT = kend / BK;
  int cur = 0;
  for (int t = 0; t < NT; ++t) {
    int nb = cur + 1; if (nb == 3) nb = 0;
    int nbase = nb * TILE_E;
    if (t + 1 < NT) {
      GLL16(gA0, la + nbase + wo0); GLL16(gA1, la + nbase + wo1);
      GLL16(gB0, lb + nbase + wo0); GLL16(gB1, lb + nbase + wo1);
      gA0 += BK; gA1 += BK; gB0 += BK; gB1 += BK;
      WAIT_VM(4);
    } else {
      WAIT_VM(0);
    }
    __builtin_amdgcn_s_barrier();
    CFENCE();
    int base = cur * TILE_E;
    short8 af[4], bf[4];
#pragma unroll
    for (int i = 0; i < 4; i++) {
      af[i] = *(const short8*)&la[base + offA[i]];
      bf[i] = *(const short8*)&lb[base + offB[i]];
    }
#pragma unroll
    for (int mi = 0; mi < 4; mi++)
#pragma unroll
      for (int ni = 0; ni < 4; ni++)
        acc[mi][ni] = __builtin_amdgcn_mfma_f32_16x16x32_bf16(af[mi], bf[ni], acc[mi][ni], 0, 0, 0);
    CFENCE();
    cur = nb;
  }

  int cw = lane & 15, rw = (lane >> 4) << 2;
#pragma unroll
  for (int mi = 0; mi < 4; mi++)
#pragma unroll
    for (int ni = 0; ni < 4; ni++)
#pragma unroll
      for (int r = 0; r < 4; r++) {
        int lrow = wm + mi * 16 + rw + r;
        int tk = ttok[lrow];
        if (tk >= 0) {
          int col = n0 + wn + ni * 16 + cw;
          atomicAdd(&out[(size_t)tk * D_DIM + col], twt[lrow] * acc[mi][ni][r]);
        }
      }
}

extern "C" void kernel_launch(void* const* d_in, const int* in_sizes, int n_in,
                              void* d_out, int out_size, void* d_ws, size_t ws_size,
                              hipStream_t stream) {
  const float* x  = (const float*)d_in[0];
  const float* gw = (const float*)d_in[1];
  const float* gb = (const float*)d_in[2];
  const float* w1 = (const float*)d_in[3];
  const float* w2 = (const float*)d_in[4];
  const float* w3 = (const float*)d_in[5];
  const float* sg = (const float*)d_in[6];
  const float* su = (const float*)d_in[7];
  const float* sd = (const float*)d_in[8];
  float* out = (float*)d_out;

  char* ws = (char*)d_ws;
  size_t off = 0;
  auto alloc = [&](size_t bytes) {
    char* p = ws + off;
    off += (bytes + 255) & ~(size_t)255;
    return p;
  };
  ushort_t* xb   = (ushort_t*)alloc((size_t)T_TOK * D_DIM * 2);
  ushort_t* w1b  = (ushort_t*)alloc((size_t)NBIG * 2);
  ushort_t* w2b  = (ushort_t*)alloc((size_t)NBIG * 2);
  ushort_t* w3b  = (ushort_t*)alloc((size_t)NBIG * 2);
  ushort_t* sgb  = (ushort_t*)alloc((size_t)NSML * 2);
  ushort_t* sub  = (ushort_t*)alloc((size_t)NSML * 2);
  ushort_t* sdb  = (ushort_t*)alloc((size_t)NSML * 2);
  float*    ew   = (float*)alloc((size_t)T_TOK * E_NUM * 4);
  ushort_t* hsh  = (ushort_t*)alloc((size_t)T_TOK * SH_DIM * 2);
  ushort_t* hbuf = (ushort_t*)alloc((size_t)MAX_TILES * BM * F_DIM * 2);
  int*      toklist = (int*)alloc((size_t)E_NUM * T_TOK * 4);
  int*      counts  = (int*)alloc(64);
  int4*     assign  = (int4*)alloc((MAX_TILES + 8) * sizeof(int4));
  int*      meta    = (int*)alloc(64);

  hipMemsetAsync(counts, 0, 64, stream);
  hipMemsetAsync(out, 0, (size_t)out_size * sizeof(float), stream);
  gate_kernel<<<T_TOK, 64, 0, stream>>>(x, gw, gb, ew, xb);
  convert_kernel<<<NCONV_CHUNKS / 256, 256, 0, stream>>>(w1, w2, w3, sg, su, sd,
                                                         w1b, w2b, w3b, sgb, sub, sdb);
  build_lists<<<(T_TOK + 255) / 256, 256, 0, stream>>>(ew, counts, toklist);
  assign_kernel<<<1, 64, 0, stream>>>(counts, assign, meta);
  up_gemm<<<UP_TOTAL, 256, 0, stream>>>(xb, sgb, sub, w1b, w3b, toklist, assign, meta,
                                        hsh, hbuf);
  down_gemm<<<DN_TOTAL, 256, 0, stream>>>(hsh, hbuf, sdb, w2b, toklist, ew, assign, meta,
                                          out);
}